// Round 6
// baseline (74.886 us; speedup 1.0000x reference)
//
#include <hip/hip_runtime.h>

typedef __attribute__((ext_vector_type(8))) short short8;
typedef __attribute__((ext_vector_type(4))) float floatx4;

#define BB 256
#define SS 512
#define VOCAB 50000
#define EMB_D 300
#define POS_MAX 512
#define POS_D 16
#define CNN_OUT 50
#define KW 5
#define NCLASS 10
#define C_IN 332            // EMB_D + 2*POS_D
#define NKS 55              // K-steps: 5 windows x 11
#define MROWS 32            // output positions per block
#define FROWS 36            // 32 outputs + 2+2 halo
#define FSTR 392            // LDS row stride in bf16 (784B == 16 mod 128 -> balanced bank walk)
#define NWF (NKS * 4 * 64 * 8)   // 112640 packed B elems

__device__ __forceinline__ unsigned short f2bf(float x) {
    unsigned u = __float_as_uint(x);
    u += 0x7FFF + ((u >> 16) & 1);      // RNE
    return (unsigned short)(u >> 16);
}

// ---------------- K0: pack conv_w -> Wf (im2col B-fragment-linear bf16), zero ymax -------
// Wf flat index ((ks*4 + nb)*64 + l)*8 + j holds W_im2col[K=(k=ks/11, c=(ks%11)*32+(l>>4)*8+j)]
//                                              [col = nb*16 + (l&15)]  (= conv_w[col][c][k])
__global__ __launch_bounds__(256) void k_prep(const float* __restrict__ conv_w,
                                              unsigned short* __restrict__ Wf,
                                              float* __restrict__ ymax) {
    int idx = blockIdx.x * 256 + threadIdx.x;
    if (idx < NWF) {
        int j = idx & 7, l = (idx >> 3) & 63, nb = (idx >> 9) & 3, ks = idx >> 11;
        int k = ks / 11;
        int c = (ks % 11) * 32 + ((l >> 4) << 3) + j;
        int col = nb * 16 + (l & 15);
        float v = 0.f;
        if (c < C_IN && col < CNN_OUT)
            v = conv_w[col * (C_IN * KW) + c * KW + k];
        Wf[idx] = f2bf(v);
    } else if (idx < NWF + BB * CNN_OUT) {
        ymax[idx - NWF] = 0.f;   // relu >= 0, so 0 is the identity for the max
    }
}

// ---------------- K1: nearest-entity distances ----------------
__global__ __launch_bounds__(512) void k_dist(const int* __restrict__ tokens,
                                              const int* __restrict__ e1p,
                                              const int* __restrict__ e2p,
                                              int* __restrict__ d1,
                                              int* __restrict__ d2) {
    __shared__ int cnt1, cnt2;
    __shared__ int lst1[SS], lst2[SS];
    int b = blockIdx.x, s = threadIdx.x;
    if (s == 0) { cnt1 = 0; cnt2 = 0; }
    __syncthreads();
    int tok = tokens[b * SS + s];
    int e1 = *e1p, e2 = *e2p;
    if (tok == e1) lst1[atomicAdd(&cnt1, 1)] = s;
    if (tok == e2) lst2[atomicAdd(&cnt2, 1)] = s;
    __syncthreads();
    int dd1 = POS_MAX - 1;
    int n1 = cnt1;
    for (int i = 0; i < n1; ++i) dd1 = min(dd1, abs(s - lst1[i]));
    int dd2 = POS_MAX - 1;
    int n2 = cnt2;
    for (int i = 0; i < n2; ++i) dd2 = min(dd2, abs(s - lst2[i]));
    d1[b * SS + s] = dd1;
    d2[b * SS + s] = dd2;
}

// ---------------- K2: fused im2col conv + relu + maxpool ----------------
// Block: 256 thr = 4 waves; tile = 32 output positions x 64 cols (50 valid) of one sentence.
// LDS 28.2 KB -> 5 blocks/CU resident (vs 53.8 KB / 2-3 before): latency hiding via TLP.
// Staging: 8 threads/row, loads batched into registers (MLP), then cvt+ds_write.
// MFMA: waves split K (14/14/14/13 of 55); per step 2 A ds_reads + 4 B loads -> 8 MFMAs.
// Cross-wave reduction of partials in 2 LDS rounds of 16 KB, then epilogue.
__global__ __launch_bounds__(256, 5) void k_fused(const int* __restrict__ tokens,
                                                  const int* __restrict__ d1,
                                                  const int* __restrict__ d2,
                                                  const float* __restrict__ E,
                                                  const float* __restrict__ pos,
                                                  const unsigned short* __restrict__ Wf,
                                                  const float* __restrict__ conv_b,
                                                  float* __restrict__ ymax) {
    __shared__ __align__(16) short F[FROWS * FSTR];   // 28,224 B
    int tid = threadIdx.x, lane = tid & 63, w = tid >> 6;
    int b = blockIdx.x >> 4, sb = blockIdx.x & 15;
    int s0 = sb * MROWS;

    // ---- stage feature rows: 8 threads per row, 32 rows/pass (pass 2: rows 32..35) ----
    int q = tid & 7;
    for (int rr = tid >> 3; rr < FROWS; rr += 32) {
        int sp = s0 - 2 + rr;
        bool valid = (sp >= 0 && sp < SS);
        int t = valid ? tokens[b * SS + sp] : 0;
        const float4* src = (const float4*)(E + (size_t)t * EMB_D);

        // phase 1: issue all E loads (10 independent float4s in flight per thread)
        float4 v[10];
        #pragma unroll
        for (int i = 0; i < 10; ++i) {
            int c4 = q + i * 8;
            v[i] = (valid && c4 < 75) ? src[c4] : make_float4(0.f, 0.f, 0.f, 0.f);
        }
        bool nz = false;
        #pragma unroll
        for (int i = 0; i < 10; ++i)
            nz |= (v[i].x != 0.f) | (v[i].y != 0.f) | (v[i].z != 0.f) | (v[i].w != 0.f);

        // phase 2: convert + LDS write
        #pragma unroll
        for (int i = 0; i < 10; ++i) {
            int c4 = q + i * 8;
            if (c4 < 75) {
                unsigned lo = ((unsigned)f2bf(v[i].y) << 16) | f2bf(v[i].x);
                unsigned hi = ((unsigned)f2bf(v[i].w) << 16) | f2bf(v[i].z);
                *(uint2*)&F[rr * FSTR + c4 * 4] = make_uint2(lo, hi);
            }
        }

        // pad-row mask: all-zero fp32 embedding row (8-lane ballot group per row)
        unsigned long long bal = __ballot(nz);
        int g = lane >> 3;
        bool rowz = (((bal >> (g * 8)) & 0xFFULL) == 0ULL);

        if (q < 2) {
            // pos features: cols 300..315 (d1) / 316..331 (d2)
            int dd = valid ? (q == 0 ? d1[b * SS + sp] : d2[b * SS + sp]) : 0;
            const float4* ps = (const float4*)(pos + dd * POS_D);
            int cbase = EMB_D + q * POS_D;
            #pragma unroll
            for (int i = 0; i < 4; ++i) {
                float4 pv = (valid && !rowz) ? ps[i] : make_float4(0.f, 0.f, 0.f, 0.f);
                unsigned lo = ((unsigned)f2bf(pv.y) << 16) | f2bf(pv.x);
                unsigned hi = ((unsigned)f2bf(pv.w) << 16) | f2bf(pv.z);
                *(uint2*)&F[rr * FSTR + cbase + i * 4] = make_uint2(lo, hi);
            }
        } else if (q < 4) {
            // zero K-pad cols 332..351 (read by MFMA as window tail)
            int cbase = C_IN + (q - 2) * 10;
            #pragma unroll
            for (int i = 0; i < 5; ++i)
                *(unsigned*)&F[rr * FSTR + cbase + i * 2] = 0u;
        }
    }
    __syncthreads();

    // ---- MFMA: wave w does K-steps [w*14, min(w*14+14, 55)), 2 m-frags x 4 n-frags ----
    floatx4 acc[2][4];
    #pragma unroll
    for (int mm = 0; mm < 2; ++mm)
        #pragma unroll
        for (int nn = 0; nn < 4; ++nn) acc[mm][nn] = (floatx4)0.f;

    int arow = lane & 15, achunk = (lane >> 4) * 8;
    const short8* Bp = (const short8*)Wf;
    int lo = w * 14;
    int hi = min(lo + 14, NKS);

    short8 bnext[4];
    #pragma unroll
    for (int nb = 0; nb < 4; ++nb)
        bnext[nb] = Bp[(lo * 4 + nb) * 64 + lane];

    for (int ks = lo; ks < hi; ++ks) {
        short8 bfrag[4];
        #pragma unroll
        for (int nb = 0; nb < 4; ++nb) bfrag[nb] = bnext[nb];
        if (ks + 1 < hi) {
            #pragma unroll
            for (int nb = 0; nb < 4; ++nb)
                bnext[nb] = Bp[((ks + 1) * 4 + nb) * 64 + lane];
        }
        int k = ks / 11, kc = ks % 11;
        const short* abase = &F[(arow + k) * FSTR + kc * 32 + achunk];
        #pragma unroll
        for (int mm = 0; mm < 2; ++mm) {
            short8 afrag = *(const short8*)(abase + mm * 16 * FSTR);
            #pragma unroll
            for (int nn = 0; nn < 4; ++nn)
                acc[mm][nn] = __builtin_amdgcn_mfma_f32_16x16x32_bf16(afrag, bfrag[nn], acc[mm][nn], 0, 0, 0);
        }
    }

    // ---- cross-wave reduction: 2 rounds of 16KB through F ----
    // round r: slot(src,nn) = src*4+nn (1KB each); wave w writes acc[r][nn], reads src*4+w
    __syncthreads();                      // all A-reads done; F reusable
    float* R = (float*)F;
    floatx4 red[2];
    #pragma unroll
    for (int round = 0; round < 2; ++round) {
        #pragma unroll
        for (int nn = 0; nn < 4; ++nn)
            *(floatx4*)&R[((w * 4 + nn) * 64 + lane) * 4] = acc[round][nn];
        __syncthreads();
        floatx4 sum0 = *(floatx4*)&R[((0 * 4 + w) * 64 + lane) * 4];
        floatx4 sum1 = *(floatx4*)&R[((1 * 4 + w) * 64 + lane) * 4];
        floatx4 sum2 = *(floatx4*)&R[((2 * 4 + w) * 64 + lane) * 4];
        floatx4 sum3 = *(floatx4*)&R[((3 * 4 + w) * 64 + lane) * 4];
        red[round] = (sum0 + sum1) + (sum2 + sum3);
        if (round == 0) __syncthreads();
    }

    // ---- bias + relu + max over rows + atomicMax (wave w owns cols w*16..w*16+15) ----
    int col = w * 16 + (lane & 15);
    float bias = (col < CNN_OUT) ? conv_b[col] : 0.f;
    float m = 0.f;                       // relu floor
    #pragma unroll
    for (int mi = 0; mi < 2; ++mi)
        #pragma unroll
        for (int rg = 0; rg < 4; ++rg)
            m = fmaxf(m, red[mi][rg] + bias);
    m = fmaxf(m, __shfl_xor(m, 16));
    m = fmaxf(m, __shfl_xor(m, 32));
    if ((lane >> 4) == 0 && col < CNN_OUT)
        atomicMax((int*)ymax + b * CNN_OUT + col, __float_as_int(m));
}

// ---------------- K4: FC ----------------
__global__ __launch_bounds__(64) void k_fc(const float* __restrict__ ymax,
                                           const float* __restrict__ fc_w,
                                           const float* __restrict__ fc_b,
                                           float* __restrict__ out) {
    int b = blockIdx.x, n = threadIdx.x;
    if (n < NCLASS) {
        float a = fc_b[n];
        #pragma unroll
        for (int o = 0; o < CNN_OUT; ++o)
            a += ymax[b * CNN_OUT + o] * fc_w[n * CNN_OUT + o];
        out[b * NCLASS + n] = a;
    }
}

extern "C" void kernel_launch(void* const* d_in, const int* in_sizes, int n_in,
                              void* d_out, int out_size, void* d_ws, size_t ws_size,
                              hipStream_t stream) {
    const int*   tokens  = (const int*)  d_in[0];
    const float* embed   = (const float*)d_in[1];
    const float* pos     = (const float*)d_in[2];
    const float* conv_w  = (const float*)d_in[3];
    const float* conv_b  = (const float*)d_in[4];
    const float* fc_w    = (const float*)d_in[5];
    const float* fc_b    = (const float*)d_in[6];
    const int*   e1p     = (const int*)  d_in[7];
    const int*   e2p     = (const int*)  d_in[8];
    float* out = (float*)d_out;

    char* ws = (char*)d_ws;
    size_t off = 0;
    unsigned short* Wf = (unsigned short*)(ws + off); off += (size_t)NWF * 2;     // 225,280
    int*   d1     = (int*)  (ws + off); off += (size_t)BB * SS * 4;
    int*   d2     = (int*)  (ws + off); off += (size_t)BB * SS * 4;
    float* ymax   = (float*)(ws + off); off += (size_t)BB * CNN_OUT * 4;
    (void)ws_size; (void)in_sizes; (void)n_in; (void)out_size;

    // K0: weight pack + ymax zero-init (every launch: atomicMax state must reset)
    {
        int total = NWF + BB * CNN_OUT;
        hipLaunchKernelGGL(k_prep, dim3((total + 255) / 256), dim3(256), 0, stream,
                           conv_w, Wf, ymax);
    }
    // K1: distances
    hipLaunchKernelGGL(k_dist, dim3(BB), dim3(512), 0, stream, tokens, e1p, e2p, d1, d2);
    // K2: fused im2col conv + relu + maxpool (32-position tiles, 5 blocks/CU)
    hipLaunchKernelGGL(k_fused, dim3(BB * (SS / MROWS)), dim3(256), 0, stream,
                       tokens, d1, d2, embed, pos, Wf, conv_b, ymax);
    // K4: FC
    hipLaunchKernelGGL(k_fc, dim3(BB), dim3(64), 0, stream, ymax, fc_w, fc_b, out);
}

// Round 7
// 68.360 us; speedup vs baseline: 1.0955x; 1.0955x over previous
//
#include <hip/hip_runtime.h>
#include <hip/hip_bf16.h>

typedef __attribute__((ext_vector_type(8))) short short8;
typedef __attribute__((ext_vector_type(4))) float floatx4;

#define BB 256
#define SS 512
#define VOCAB 50000
#define EMB_D 300
#define POS_MAX 512
#define POS_D 16
#define CNN_OUT 50
#define KW 5
#define NCLASS 10
#define C_IN 332            // EMB_D + 2*POS_D
#define NKS 55              // K-steps: 5 windows x 11
#define MROWS 64            // output positions per block
#define FROWS 68            // 64 outputs + 2+2 halo
#define FSTR 392            // LDS row stride in bf16 (784B == 16 mod 128 -> balanced bank walk)
#define NWF (NKS * 4 * 64 * 8)   // 112640 packed B elems

__device__ __forceinline__ unsigned pack2bf(float x, float y) {
    __hip_bfloat162 h = __float22bfloat162_rn(make_float2(x, y));   // v_cvt_pk_bf16_f32
    return *reinterpret_cast<unsigned*>(&h);
}

__device__ __forceinline__ unsigned short f2bf(float x) {
    unsigned u = __float_as_uint(x);
    u += 0x7FFF + ((u >> 16) & 1);      // RNE (host-free path, k_prep only)
    return (unsigned short)(u >> 16);
}

// ---------------- K0: pack conv_w -> Wf (im2col B-fragment-linear bf16), zero ymax -------
// Wf flat index ((ks*4 + nb)*64 + l)*8 + j holds W_im2col[K=(k=ks/11, c=(ks%11)*32+(l>>4)*8+j)]
//                                              [col = nb*16 + (l&15)]  (= conv_w[col][c][k])
__global__ __launch_bounds__(256) void k_prep(const float* __restrict__ conv_w,
                                              unsigned short* __restrict__ Wf,
                                              float* __restrict__ ymax) {
    int idx = blockIdx.x * 256 + threadIdx.x;
    if (idx < NWF) {
        int j = idx & 7, l = (idx >> 3) & 63, nb = (idx >> 9) & 3, ks = idx >> 11;
        int k = ks / 11;
        int c = (ks % 11) * 32 + ((l >> 4) << 3) + j;
        int col = nb * 16 + (l & 15);
        float v = 0.f;
        if (c < C_IN && col < CNN_OUT)
            v = conv_w[col * (C_IN * KW) + c * KW + k];
        Wf[idx] = f2bf(v);
    } else if (idx < NWF + BB * CNN_OUT) {
        ymax[idx - NWF] = 0.f;   // relu >= 0, so 0 is the identity for the max
    }
}

// ---------------- K1: nearest-entity distances ----------------
__global__ __launch_bounds__(512) void k_dist(const int* __restrict__ tokens,
                                              const int* __restrict__ e1p,
                                              const int* __restrict__ e2p,
                                              int* __restrict__ d1,
                                              int* __restrict__ d2) {
    __shared__ int cnt1, cnt2;
    __shared__ int lst1[SS], lst2[SS];
    int b = blockIdx.x, s = threadIdx.x;
    if (s == 0) { cnt1 = 0; cnt2 = 0; }
    __syncthreads();
    int tok = tokens[b * SS + s];
    int e1 = *e1p, e2 = *e2p;
    if (tok == e1) lst1[atomicAdd(&cnt1, 1)] = s;
    if (tok == e2) lst2[atomicAdd(&cnt2, 1)] = s;
    __syncthreads();
    int dd1 = POS_MAX - 1;
    int n1 = cnt1;
    for (int i = 0; i < n1; ++i) dd1 = min(dd1, abs(s - lst1[i]));
    int dd2 = POS_MAX - 1;
    int n2 = cnt2;
    for (int i = 0; i < n2; ++i) dd2 = min(dd2, abs(s - lst2[i]));
    d1[b * SS + s] = dd1;
    d2[b * SS + s] = dd2;
}

// ---------------- K2: fused im2col conv + relu + maxpool ----------------
// Block: 256 thr = 4 waves; tile = 64 output positions x 64 cols (50 valid) of one sentence.
// Staging (de-serialized): E loads + d-index loads issued together; pos gather issued as
// soon as the index lands; rowz applied as a post-mask. One latency hop, not three.
// MFMA: waves split K (14/14/14/13 of 55); 2-deep B prefetch via unroll-by-2 ping-pong.
// Cross-wave reduction of partials in 2 LDS rounds of 32 KB, then epilogue.
__global__ __launch_bounds__(256, 3) void k_fused(const int* __restrict__ tokens,
                                                  const int* __restrict__ d1,
                                                  const int* __restrict__ d2,
                                                  const float* __restrict__ E,
                                                  const float* __restrict__ pos,
                                                  const unsigned short* __restrict__ Wf,
                                                  const float* __restrict__ conv_b,
                                                  float* __restrict__ ymax) {
    __shared__ __align__(16) short F[FROWS * FSTR];   // 53,312 B
    int tid = threadIdx.x, lane = tid & 63, w = tid >> 6;
    int b = blockIdx.x >> 3, sb = blockIdx.x & 7;
    int s0 = sb * MROWS;

    // ---- stage feature rows: 8 threads per row, 32 rows/pass ----
    int q = tid & 7;
    for (int rr = tid >> 3; rr < FROWS; rr += 32) {
        int sp = s0 - 2 + rr;
        bool valid = (sp >= 0 && sp < SS);
        int t = valid ? tokens[b * SS + sp] : 0;
        const float4* src = (const float4*)(E + (size_t)t * EMB_D);

        // phase 1: issue E loads AND the distance-index load together
        int dd = 0;
        if (q < 2)
            dd = valid ? (q == 0 ? d1[b * SS + sp] : d2[b * SS + sp]) : 0;
        float4 v[10];
        #pragma unroll
        for (int i = 0; i < 10; ++i) {
            int c4 = q + i * 8;
            v[i] = (valid && c4 < 75) ? src[c4] : make_float4(0.f, 0.f, 0.f, 0.f);
        }
        // phase 1b: pos gather issues as soon as dd lands (unmasked; mask applied later)
        float4 pv[4];
        if (q < 2) {
            const float4* ps = (const float4*)(pos + dd * POS_D);
            #pragma unroll
            for (int i = 0; i < 4; ++i)
                pv[i] = valid ? ps[i] : make_float4(0.f, 0.f, 0.f, 0.f);
        }

        // phase 2: convert + LDS write E (VALU overlaps the pos-gather latency)
        bool nz = false;
        #pragma unroll
        for (int i = 0; i < 10; ++i)
            nz |= (v[i].x != 0.f) | (v[i].y != 0.f) | (v[i].z != 0.f) | (v[i].w != 0.f);
        #pragma unroll
        for (int i = 0; i < 10; ++i) {
            int c4 = q + i * 8;
            if (c4 < 75)
                *(uint2*)&F[rr * FSTR + c4 * 4] =
                    make_uint2(pack2bf(v[i].x, v[i].y), pack2bf(v[i].z, v[i].w));
        }

        // pad-row mask: all-zero fp32 embedding row (8-lane ballot group per row)
        unsigned long long bal = __ballot(nz);
        int g = lane >> 3;
        bool rowz = (((bal >> (g * 8)) & 0xFFULL) == 0ULL);

        if (q < 2) {
            // pos features: cols 300..315 (d1) / 316..331 (d2); post-mask by pad row
            float msk = (valid && !rowz) ? 1.f : 0.f;
            int cbase = EMB_D + q * POS_D;
            #pragma unroll
            for (int i = 0; i < 4; ++i)
                *(uint2*)&F[rr * FSTR + cbase + i * 4] =
                    make_uint2(pack2bf(pv[i].x * msk, pv[i].y * msk),
                               pack2bf(pv[i].z * msk, pv[i].w * msk));
        } else if (q < 4) {
            // zero K-pad cols 332..351 (read by MFMA as window tail)
            int cbase = C_IN + (q - 2) * 10;
            #pragma unroll
            for (int i = 0; i < 5; ++i)
                *(unsigned*)&F[rr * FSTR + cbase + i * 2] = 0u;
        }
    }
    __syncthreads();

    // ---- MFMA: wave w does K-steps [w*14, min(w*14+14, 55)), all 4x4 fragments ----
    floatx4 acc[4][4];
    #pragma unroll
    for (int mm = 0; mm < 4; ++mm)
        #pragma unroll
        for (int nn = 0; nn < 4; ++nn) acc[mm][nn] = (floatx4)0.f;

    int arow = lane & 15, achunk = (lane >> 4) * 8;
    const short8* Bp = (const short8*)Wf;
    int lo = w * 14;
    int hi = min(lo + 14, NKS);

    short8 bA[4], bB[4];
    #pragma unroll
    for (int nb = 0; nb < 4; ++nb)
        bA[nb] = Bp[(lo * 4 + nb) * 64 + lane];
    if (lo + 1 < hi) {
        #pragma unroll
        for (int nb = 0; nb < 4; ++nb)
            bB[nb] = Bp[((lo + 1) * 4 + nb) * 64 + lane];
    }

    auto step = [&](int ks, short8 (&bf)[4], int pfks) {
        int k = ks / 11, kc = ks % 11;
        const short* abase = &F[(arow + k) * FSTR + kc * 32 + achunk];
        #pragma unroll
        for (int mm = 0; mm < 4; ++mm) {
            short8 afrag = *(const short8*)(abase + mm * 16 * FSTR);
            #pragma unroll
            for (int nn = 0; nn < 4; ++nn)
                acc[mm][nn] = __builtin_amdgcn_mfma_f32_16x16x32_bf16(afrag, bf[nn], acc[mm][nn], 0, 0, 0);
        }
        if (pfks < hi) {
            #pragma unroll
            for (int nb = 0; nb < 4; ++nb)
                bf[nb] = Bp[(pfks * 4 + nb) * 64 + lane];
        }
    };

    int ks = lo;
    for (; ks + 1 < hi; ks += 2) {
        step(ks, bA, ks + 2);
        step(ks + 1, bB, ks + 3);
    }
    if (ks < hi) step(ks, bA, NKS);   // tail, no prefetch

    // ---- cross-wave reduction: 2 rounds of 32KB through F ----
    // slot = src*8 + i*4 + nn  (i = mm within round); each slot = 64 lanes x 16B
    __syncthreads();                      // all A-reads done; F reusable
    float* R = (float*)F;
    floatx4 red[4];
    #pragma unroll
    for (int round = 0; round < 2; ++round) {
        #pragma unroll
        for (int i = 0; i < 2; ++i)
            #pragma unroll
            for (int nn = 0; nn < 4; ++nn)
                *(floatx4*)&R[((w * 8 + i * 4 + nn) * 64 + lane) * 4] = acc[round * 2 + i][nn];
        __syncthreads();
        #pragma unroll
        for (int i = 0; i < 2; ++i) {
            floatx4 t0 = *(floatx4*)&R[((0 * 8 + i * 4 + w) * 64 + lane) * 4];
            floatx4 t1 = *(floatx4*)&R[((1 * 8 + i * 4 + w) * 64 + lane) * 4];
            floatx4 t2 = *(floatx4*)&R[((2 * 8 + i * 4 + w) * 64 + lane) * 4];
            floatx4 t3 = *(floatx4*)&R[((3 * 8 + i * 4 + w) * 64 + lane) * 4];
            red[round * 2 + i] = (t0 + t1) + (t2 + t3);
        }
        if (round == 0) __syncthreads();
    }

    // ---- bias + relu + max over rows + atomicMax (wave w owns cols w*16..w*16+15) ----
    int col = w * 16 + (lane & 15);
    float bias = (col < CNN_OUT) ? conv_b[col] : 0.f;
    float m = 0.f;                       // relu floor
    #pragma unroll
    for (int mi = 0; mi < 4; ++mi)
        #pragma unroll
        for (int rg = 0; rg < 4; ++rg)
            m = fmaxf(m, red[mi][rg] + bias);
    m = fmaxf(m, __shfl_xor(m, 16));
    m = fmaxf(m, __shfl_xor(m, 32));
    if ((lane >> 4) == 0 && col < CNN_OUT)
        atomicMax((int*)ymax + b * CNN_OUT + col, __float_as_int(m));
}

// ---------------- K4: FC ----------------
__global__ __launch_bounds__(64) void k_fc(const float* __restrict__ ymax,
                                           const float* __restrict__ fc_w,
                                           const float* __restrict__ fc_b,
                                           float* __restrict__ out) {
    int b = blockIdx.x, n = threadIdx.x;
    if (n < NCLASS) {
        float a = fc_b[n];
        #pragma unroll
        for (int o = 0; o < CNN_OUT; ++o)
            a += ymax[b * CNN_OUT + o] * fc_w[n * CNN_OUT + o];
        out[b * NCLASS + n] = a;
    }
}

extern "C" void kernel_launch(void* const* d_in, const int* in_sizes, int n_in,
                              void* d_out, int out_size, void* d_ws, size_t ws_size,
                              hipStream_t stream) {
    const int*   tokens  = (const int*)  d_in[0];
    const float* embed   = (const float*)d_in[1];
    const float* pos     = (const float*)d_in[2];
    const float* conv_w  = (const float*)d_in[3];
    const float* conv_b  = (const float*)d_in[4];
    const float* fc_w    = (const float*)d_in[5];
    const float* fc_b    = (const float*)d_in[6];
    const int*   e1p     = (const int*)  d_in[7];
    const int*   e2p     = (const int*)  d_in[8];
    float* out = (float*)d_out;

    char* ws = (char*)d_ws;
    size_t off = 0;
    unsigned short* Wf = (unsigned short*)(ws + off); off += (size_t)NWF * 2;     // 225,280
    int*   d1     = (int*)  (ws + off); off += (size_t)BB * SS * 4;
    int*   d2     = (int*)  (ws + off); off += (size_t)BB * SS * 4;
    float* ymax   = (float*)(ws + off); off += (size_t)BB * CNN_OUT * 4;
    (void)ws_size; (void)in_sizes; (void)n_in; (void)out_size;

    // K0: weight pack + ymax zero-init (every launch: atomicMax state must reset)
    {
        int total = NWF + BB * CNN_OUT;
        hipLaunchKernelGGL(k_prep, dim3((total + 255) / 256), dim3(256), 0, stream,
                           conv_w, Wf, ymax);
    }
    // K1: distances
    hipLaunchKernelGGL(k_dist, dim3(BB), dim3(512), 0, stream, tokens, e1p, e2p, d1, d2);
    // K2: fused im2col conv + relu + maxpool (64-position tiles, 3 blocks/CU)
    hipLaunchKernelGGL(k_fused, dim3(BB * (SS / MROWS)), dim3(256), 0, stream,
                       tokens, d1, d2, embed, pos, Wf, conv_b, ymax);
    // K4: FC
    hipLaunchKernelGGL(k_fc, dim3(BB), dim3(64), 0, stream, ymax, fc_w, fc_b, out);
}

// Round 8
// 67.335 us; speedup vs baseline: 1.1122x; 1.0152x over previous
//
#include <hip/hip_runtime.h>
#include <hip/hip_bf16.h>

typedef __attribute__((ext_vector_type(8))) short short8;
typedef __attribute__((ext_vector_type(4))) float floatx4;

#define BB 256
#define SS 512
#define VOCAB 50000
#define EMB_D 300
#define POS_MAX 512
#define POS_D 16
#define CNN_OUT 50
#define KW 5
#define NCLASS 10
#define C_IN 332            // EMB_D + 2*POS_D
#define NKS 55              // K-steps: 5 windows x 11
#define MROWS 64            // output positions per block
#define FROWS 68            // 64 outputs + 2+2 halo
#define FSTR 392            // LDS row stride in bf16 (784B == 16 mod 128 -> balanced bank walk)
#define E2STR 320           // bf16 E row stride: 640 B = exactly 5 x 128B lines, aligned
#define NWF (NKS * 4 * 64 * 8)   // 112640 packed B elems

__device__ __forceinline__ unsigned pack2bf(float x, float y) {
    __hip_bfloat162 h = __float22bfloat162_rn(make_float2(x, y));   // v_cvt_pk_bf16_f32
    return *reinterpret_cast<unsigned*>(&h);
}

__device__ __forceinline__ unsigned short f2bf(float x) {
    unsigned u = __float_as_uint(x);
    u += 0x7FFF + ((u >> 16) & 1);      // RNE (k_prep only)
    return (unsigned short)(u >> 16);
}

// ---------------- K-1: E fp32 -> E2 bf16 (stride 320, 128B-aligned rows) ----------------
__global__ __launch_bounds__(256) void k_cvt(const float* __restrict__ E,
                                             unsigned short* __restrict__ E2) {
    int row = blockIdx.x * 4 + (threadIdx.x >> 6);
    if (row >= VOCAB) return;
    int lane = threadIdx.x & 63;
    const float4* src = (const float4*)(E + (size_t)row * EMB_D);
    unsigned short* dst = E2 + (size_t)row * E2STR;
    float4 a = src[lane];                                   // elems 4L..4L+3 (L<75 always)
    *(uint2*)&dst[lane * 4] = make_uint2(pack2bf(a.x, a.y), pack2bf(a.z, a.w));
    if (lane < 11) {
        float4 bq = src[64 + lane];                         // elems 256..299
        *(uint2*)&dst[256 + lane * 4] = make_uint2(pack2bf(bq.x, bq.y), pack2bf(bq.z, bq.w));
    } else if (lane < 16) {
        *(uint2*)&dst[300 + (lane - 11) * 4] = make_uint2(0u, 0u);   // pad elems 300..319
    }
}

// ---------------- K0: pack conv_w -> Wf (im2col B-fragment-linear bf16), zero ymax -------
__global__ __launch_bounds__(256) void k_prep(const float* __restrict__ conv_w,
                                              unsigned short* __restrict__ Wf,
                                              float* __restrict__ ymax) {
    int idx = blockIdx.x * 256 + threadIdx.x;
    if (idx < NWF) {
        int j = idx & 7, l = (idx >> 3) & 63, nb = (idx >> 9) & 3, ks = idx >> 11;
        int k = ks / 11;
        int c = (ks % 11) * 32 + ((l >> 4) << 3) + j;
        int col = nb * 16 + (l & 15);
        float v = 0.f;
        if (c < C_IN && col < CNN_OUT)
            v = conv_w[col * (C_IN * KW) + c * KW + k];
        Wf[idx] = f2bf(v);
    } else if (idx < NWF + BB * CNN_OUT) {
        ymax[idx - NWF] = 0.f;   // relu >= 0, so 0 is the identity for the max
    }
}

// ---------------- K1: nearest-entity distances ----------------
__global__ __launch_bounds__(512) void k_dist(const int* __restrict__ tokens,
                                              const int* __restrict__ e1p,
                                              const int* __restrict__ e2p,
                                              int* __restrict__ d1,
                                              int* __restrict__ d2) {
    __shared__ int cnt1, cnt2;
    __shared__ int lst1[SS], lst2[SS];
    int b = blockIdx.x, s = threadIdx.x;
    if (s == 0) { cnt1 = 0; cnt2 = 0; }
    __syncthreads();
    int tok = tokens[b * SS + s];
    int e1 = *e1p, e2 = *e2p;
    if (tok == e1) lst1[atomicAdd(&cnt1, 1)] = s;
    if (tok == e2) lst2[atomicAdd(&cnt2, 1)] = s;
    __syncthreads();
    int dd1 = POS_MAX - 1;
    int n1 = cnt1;
    for (int i = 0; i < n1; ++i) dd1 = min(dd1, abs(s - lst1[i]));
    int dd2 = POS_MAX - 1;
    int n2 = cnt2;
    for (int i = 0; i < n2; ++i) dd2 = min(dd2, abs(s - lst2[i]));
    d1[b * SS + s] = dd1;
    d2[b * SS + s] = dd2;
}

// ---------------- K2: fused im2col conv + relu + maxpool ----------------
// Block: 256 thr = 4 waves; tile = 64 output positions x 64 cols (50 valid) of one sentence.
// Staging (single-pass, bf16 source): 4 threads/row, 10 uint4 loads in flight per thread,
// straight bit-copy into LDS (no cvt); pos gather overlapped; rowz via bit-mask ballot.
// MFMA: waves split K (14/14/14/13 of 55); 2-deep B prefetch via unroll-by-2 ping-pong.
// Cross-wave reduction of partials in 2 LDS rounds of 32 KB, then epilogue.
__global__ __launch_bounds__(256, 3) void k_fused(const int* __restrict__ tokens,
                                                  const int* __restrict__ d1,
                                                  const int* __restrict__ d2,
                                                  const unsigned short* __restrict__ E2,
                                                  const float* __restrict__ pos,
                                                  const unsigned short* __restrict__ Wf,
                                                  const float* __restrict__ conv_b,
                                                  float* __restrict__ ymax) {
    __shared__ __align__(16) short F[FROWS * FSTR];   // 53,312 B
    int tid = threadIdx.x, lane = tid & 63, w = tid >> 6;
    int b = blockIdx.x >> 3, sb = blockIdx.x & 7;
    int s0 = sb * MROWS;

    // ---- stage feature rows: 4 threads/row, 64 rows in pass 1, rows 64..67 in pass 2 ----
    int q = tid & 3;
    for (int rr = tid >> 2; rr < FROWS; rr += 64) {
        int sp = s0 - 2 + rr;
        bool valid = (sp >= 0 && sp < SS);
        int t = valid ? tokens[b * SS + sp] : 0;
        const uint4* src = (const uint4*)(E2 + (size_t)t * E2STR);   // 40 chunks of 8 bf16

        // distance index issued alongside E loads
        int dd = 0;
        if (q < 2)
            dd = valid ? (q == 0 ? d1[b * SS + sp] : d2[b * SS + sp]) : 0;

        // phase 1: 10 independent uint4 loads in flight
        uint4 v[10];
        #pragma unroll
        for (int i = 0; i < 10; ++i) {
            int c4 = q + i * 4;
            v[i] = valid ? src[c4] : make_uint4(0u, 0u, 0u, 0u);
        }
        // pos gather issues as soon as dd lands (mask applied later)
        float4 pv[4];
        if (q < 2) {
            const float4* ps = (const float4*)(pos + dd * POS_D);
            #pragma unroll
            for (int i = 0; i < 4; ++i)
                pv[i] = valid ? ps[i] : make_float4(0.f, 0.f, 0.f, 0.f);
        }

        // phase 2: zero-test (bit mask kills ±0) + straight LDS copy
        unsigned nzb = 0;
        #pragma unroll
        for (int i = 0; i < 10; ++i)
            nzb |= (v[i].x | v[i].y | v[i].z | v[i].w);
        bool nz = (nzb & 0x7FFF7FFFu) != 0u;
        #pragma unroll
        for (int i = 0; i < 10; ++i) {
            int c4 = q + i * 4;
            if (c4 <= 36) {
                *(uint4*)&F[rr * FSTR + c4 * 8] = v[i];
            } else if (c4 == 37) {   // elems 296..299 only (300+ belong to pos cols)
                *(uint2*)&F[rr * FSTR + 296] = make_uint2(v[i].x, v[i].y);
            }
        }

        // pad-row mask: all-zero embedding row (4-lane ballot group per row)
        unsigned long long bal = __ballot(nz);
        int g = lane >> 2;
        bool rowz = (((bal >> (g * 4)) & 0xFULL) == 0ULL);

        if (q < 2) {
            // pos features: cols 300..315 (d1) / 316..331 (d2); post-mask by pad row
            float msk = (valid && !rowz) ? 1.f : 0.f;
            int cbase = EMB_D + q * POS_D;
            #pragma unroll
            for (int i = 0; i < 4; ++i)
                *(uint2*)&F[rr * FSTR + cbase + i * 4] =
                    make_uint2(pack2bf(pv[i].x * msk, pv[i].y * msk),
                               pack2bf(pv[i].z * msk, pv[i].w * msk));
        } else {
            // zero K-pad cols 332..351 (read by MFMA as window tail)
            int cbase = C_IN + (q - 2) * 10;
            #pragma unroll
            for (int i = 0; i < 5; ++i)
                *(unsigned*)&F[rr * FSTR + cbase + i * 2] = 0u;
        }
    }
    __syncthreads();

    // ---- MFMA: wave w does K-steps [w*14, min(w*14+14, 55)), all 4x4 fragments ----
    floatx4 acc[4][4];
    #pragma unroll
    for (int mm = 0; mm < 4; ++mm)
        #pragma unroll
        for (int nn = 0; nn < 4; ++nn) acc[mm][nn] = (floatx4)0.f;

    int arow = lane & 15, achunk = (lane >> 4) * 8;
    const short8* Bp = (const short8*)Wf;
    int lo = w * 14;
    int hi = min(lo + 14, NKS);

    short8 bA[4], bB[4];
    #pragma unroll
    for (int nb = 0; nb < 4; ++nb)
        bA[nb] = Bp[(lo * 4 + nb) * 64 + lane];
    if (lo + 1 < hi) {
        #pragma unroll
        for (int nb = 0; nb < 4; ++nb)
            bB[nb] = Bp[((lo + 1) * 4 + nb) * 64 + lane];
    }

    auto step = [&](int ks, short8 (&bf)[4], int pfks) {
        int k = ks / 11, kc = ks % 11;
        const short* abase = &F[(arow + k) * FSTR + kc * 32 + achunk];
        #pragma unroll
        for (int mm = 0; mm < 4; ++mm) {
            short8 afrag = *(const short8*)(abase + mm * 16 * FSTR);
            #pragma unroll
            for (int nn = 0; nn < 4; ++nn)
                acc[mm][nn] = __builtin_amdgcn_mfma_f32_16x16x32_bf16(afrag, bf[nn], acc[mm][nn], 0, 0, 0);
        }
        if (pfks < hi) {
            #pragma unroll
            for (int nb = 0; nb < 4; ++nb)
                bf[nb] = Bp[(pfks * 4 + nb) * 64 + lane];
        }
    };

    int ks = lo;
    for (; ks + 1 < hi; ks += 2) {
        step(ks, bA, ks + 2);
        step(ks + 1, bB, ks + 3);
    }
    if (ks < hi) step(ks, bA, NKS);   // tail, no prefetch

    // ---- cross-wave reduction: 2 rounds of 32KB through F ----
    __syncthreads();                      // all A-reads done; F reusable
    float* R = (float*)F;
    floatx4 red[4];
    #pragma unroll
    for (int round = 0; round < 2; ++round) {
        #pragma unroll
        for (int i = 0; i < 2; ++i)
            #pragma unroll
            for (int nn = 0; nn < 4; ++nn)
                *(floatx4*)&R[((w * 8 + i * 4 + nn) * 64 + lane) * 4] = acc[round * 2 + i][nn];
        __syncthreads();
        #pragma unroll
        for (int i = 0; i < 2; ++i) {
            floatx4 t0 = *(floatx4*)&R[((0 * 8 + i * 4 + w) * 64 + lane) * 4];
            floatx4 t1 = *(floatx4*)&R[((1 * 8 + i * 4 + w) * 64 + lane) * 4];
            floatx4 t2 = *(floatx4*)&R[((2 * 8 + i * 4 + w) * 64 + lane) * 4];
            floatx4 t3 = *(floatx4*)&R[((3 * 8 + i * 4 + w) * 64 + lane) * 4];
            red[round * 2 + i] = (t0 + t1) + (t2 + t3);
        }
        if (round == 0) __syncthreads();
    }

    // ---- bias + relu + max over rows + atomicMax (wave w owns cols w*16..w*16+15) ----
    int col = w * 16 + (lane & 15);
    float bias = (col < CNN_OUT) ? conv_b[col] : 0.f;
    float m = 0.f;                       // relu floor
    #pragma unroll
    for (int mi = 0; mi < 4; ++mi)
        #pragma unroll
        for (int rg = 0; rg < 4; ++rg)
            m = fmaxf(m, red[mi][rg] + bias);
    m = fmaxf(m, __shfl_xor(m, 16));
    m = fmaxf(m, __shfl_xor(m, 32));
    if ((lane >> 4) == 0 && col < CNN_OUT)
        atomicMax((int*)ymax + b * CNN_OUT + col, __float_as_int(m));
}

// ---------------- K4: FC ----------------
__global__ __launch_bounds__(64) void k_fc(const float* __restrict__ ymax,
                                           const float* __restrict__ fc_w,
                                           const float* __restrict__ fc_b,
                                           float* __restrict__ out) {
    int b = blockIdx.x, n = threadIdx.x;
    if (n < NCLASS) {
        float a = fc_b[n];
        #pragma unroll
        for (int o = 0; o < CNN_OUT; ++o)
            a += ymax[b * CNN_OUT + o] * fc_w[n * CNN_OUT + o];
        out[b * NCLASS + n] = a;
    }
}

extern "C" void kernel_launch(void* const* d_in, const int* in_sizes, int n_in,
                              void* d_out, int out_size, void* d_ws, size_t ws_size,
                              hipStream_t stream) {
    const int*   tokens  = (const int*)  d_in[0];
    const float* embed   = (const float*)d_in[1];
    const float* pos     = (const float*)d_in[2];
    const float* conv_w  = (const float*)d_in[3];
    const float* conv_b  = (const float*)d_in[4];
    const float* fc_w    = (const float*)d_in[5];
    const float* fc_b    = (const float*)d_in[6];
    const int*   e1p     = (const int*)  d_in[7];
    const int*   e2p     = (const int*)  d_in[8];
    float* out = (float*)d_out;

    char* ws = (char*)d_ws;
    size_t off = 0;
    unsigned short* E2 = (unsigned short*)(ws + off); off += (size_t)VOCAB * E2STR * 2; // 32,000,000 (128B-aligned rows)
    unsigned short* Wf = (unsigned short*)(ws + off); off += (size_t)NWF * 2;           // 225,280
    int*   d1     = (int*)  (ws + off); off += (size_t)BB * SS * 4;
    int*   d2     = (int*)  (ws + off); off += (size_t)BB * SS * 4;
    float* ymax   = (float*)(ws + off); off += (size_t)BB * CNN_OUT * 4;
    (void)ws_size; (void)in_sizes; (void)n_in; (void)out_size;

    // K-1: E -> bf16 (biggest prep; runs while nothing depends on it yet)
    hipLaunchKernelGGL(k_cvt, dim3((VOCAB + 3) / 4), dim3(256), 0, stream, embed, E2);
    // K0: weight pack + ymax zero-init (every launch: atomicMax state must reset)
    {
        int total = NWF + BB * CNN_OUT;
        hipLaunchKernelGGL(k_prep, dim3((total + 255) / 256), dim3(256), 0, stream,
                           conv_w, Wf, ymax);
    }
    // K1: distances
    hipLaunchKernelGGL(k_dist, dim3(BB), dim3(512), 0, stream, tokens, e1p, e2p, d1, d2);
    // K2: fused im2col conv + relu + maxpool (64-position tiles, 3 blocks/CU)
    hipLaunchKernelGGL(k_fused, dim3(BB * (SS / MROWS)), dim3(256), 0, stream,
                       tokens, d1, d2, E2, pos, Wf, conv_b, ymax);
    // K4: FC
    hipLaunchKernelGGL(k_fc, dim3(BB), dim3(64), 0, stream, ymax, fc_w, fc_b, out);
}